// Round 6
// baseline (297.292 us; speedup 1.0000x reference)
//
#include <hip/hip_runtime.h>
#include <hip/hip_cooperative_groups.h>

namespace cg = cooperative_groups;

#define NN    100000
#define NE    1600000
#define D     128
#define P     16                 // edge slices
#define BINS  16                 // node bins
#define BSZ   6256               // nodes per bin (25 KB LDS); BINS*BSZ = 100096 >= NN
#define NNP   (BINS * BSZ)       // padded node stride
#define NNP4  (NNP / 4)
#define SL4   (NE / 4 / P)       // int4 edges per slice = 25000 (exact)
#define CH4   98                 // float4 node-chunk per block in ph2/ph4 (256*98*4 >= NNP)
#define GRID  (BINS * P)         // 256 blocks = 1/CU (cooperative co-residency)

// One cooperative kernel, 5 phases separated by grid.sync():
//  ph1 deg scatter (LDS bins, no global atomics) -> pA partials
//  ph2 dinv = rsqrt(1+deg); s1 = colsum(W1); accg = 0
//  ph3 fused S/U scatter: S[v]=sum_{col=v} w*dinv[row], U[v]=sum_{row=v} w*dinv[col]
//  ph4 c=dinv*(S+dinv), wgt=dinv*(U+dinv) (never materialized) + node-dot -> accg
//  ph5 gemv: out = accg @ W2 / N + b2
__global__ __launch_bounds__(1024, 4) void k_fused(
    const int4* __restrict__ col4, const int4* __restrict__ row4,
    const float4* __restrict__ w4,
    const float* __restrict__ W1, const float* __restrict__ b1,
    const float* __restrict__ W2, const float* __restrict__ b2,
    float* __restrict__ pA, float* __restrict__ pB,
    float* __restrict__ dinv, float* __restrict__ s1g,
    float* __restrict__ accg, float* __restrict__ out)
{
    __shared__ float binS[BSZ];
    __shared__ float binU[BSZ];
    __shared__ float red[1024];
    __shared__ float ldsC[CH4 * 4];
    __shared__ float ldsW[CH4 * 4];

    cg::grid_group grid = cg::this_grid();
    const int tid = threadIdx.x;
    const int blk = blockIdx.x;
    const int s   = blk & (BINS - 1);  // slice; co-slice blocks share an XCD (blk%8 == s%8)
    const int b   = blk >> 4;          // bin
    const int lo  = b * BSZ;
    float4* bS4 = (float4*)binS;
    float4* bU4 = (float4*)binU;

    // ---------------- ph1: degree scatter (key=col, val=w) ----------------
    for (int i = tid; i < BSZ / 4; i += 1024) bS4[i] = make_float4(0.f, 0.f, 0.f, 0.f);
    __syncthreads();
    {
        const int e1 = (s + 1) * SL4;
        for (int e = s * SL4 + tid; e < e1; e += 1024) {
            int4 k = col4[e];
            float4 v = w4[e];
            int r0 = k.x - lo, r1 = k.y - lo, r2 = k.z - lo, r3 = k.w - lo;
            if ((unsigned)r0 < (unsigned)BSZ) atomicAdd(&binS[r0], v.x);
            if ((unsigned)r1 < (unsigned)BSZ) atomicAdd(&binS[r1], v.y);
            if ((unsigned)r2 < (unsigned)BSZ) atomicAdd(&binS[r2], v.z);
            if ((unsigned)r3 < (unsigned)BSZ) atomicAdd(&binS[r3], v.w);
        }
    }
    __syncthreads();
    {
        float4* dst = (float4*)(pA + (size_t)s * NNP + lo);
        for (int i = tid; i < BSZ / 4; i += 1024) dst[i] = bS4[i];
    }
    grid.sync();

    // ---------------- ph2: dinv + s1 + zero accg ----------------
    {
        int v4 = blk * CH4 + tid;
        if (tid < CH4 && v4 < NNP4) {
            float4 a = make_float4(1.f, 1.f, 1.f, 1.f);   // self-loop weight
            #pragma unroll
            for (int ss = 0; ss < P; ++ss) {
                float4 p = ((const float4*)(pA + (size_t)ss * NNP))[v4];
                a.x += p.x; a.y += p.y; a.z += p.z; a.w += p.w;
            }
            float4 r;
            r.x = rsqrtf(a.x); r.y = rsqrtf(a.y); r.z = rsqrtf(a.z); r.w = rsqrtf(a.w);
            ((float4*)dinv)[v4] = r;
        }
        if (blk == 1) {                       // s1[j] = sum_i W1[i][j], parallel 8x128
            int rr = tid >> 7, j = tid & (D - 1);
            float p = 0.f;
            #pragma unroll
            for (int k = 0; k < D / 8; ++k) p += W1[(rr + k * 8) * D + j];
            red[tid] = p;
            __syncthreads();
            if (tid < D) {
                float t = 0.f;
                #pragma unroll
                for (int k = 0; k < 8; ++k) t += red[k * D + tid];
                s1g[tid] = t;
                accg[tid] = 0.f;              // ws is poisoned each call
            }
        }
    }
    grid.sync();

    // ---------------- ph3: fused S/U scatter ----------------
    for (int i = tid; i < BSZ / 4; i += 1024) {
        bS4[i] = make_float4(0.f, 0.f, 0.f, 0.f);
        bU4[i] = make_float4(0.f, 0.f, 0.f, 0.f);
    }
    __syncthreads();
    {
        const int e1 = (s + 1) * SL4;
        for (int e = s * SL4 + tid; e < e1; e += 1024) {
            int4 kc = col4[e];
            int4 kr = row4[e];
            float4 w = w4[e];
            int c0 = kc.x - lo, c1 = kc.y - lo, c2 = kc.z - lo, c3 = kc.w - lo;
            int r0 = kr.x - lo, r1 = kr.y - lo, r2 = kr.z - lo, r3 = kr.w - lo;
            if ((unsigned)c0 < (unsigned)BSZ) atomicAdd(&binS[c0], w.x * dinv[kr.x]);
            if ((unsigned)c1 < (unsigned)BSZ) atomicAdd(&binS[c1], w.y * dinv[kr.y]);
            if ((unsigned)c2 < (unsigned)BSZ) atomicAdd(&binS[c2], w.z * dinv[kr.z]);
            if ((unsigned)c3 < (unsigned)BSZ) atomicAdd(&binS[c3], w.w * dinv[kr.w]);
            if ((unsigned)r0 < (unsigned)BSZ) atomicAdd(&binU[r0], w.x * dinv[kc.x]);
            if ((unsigned)r1 < (unsigned)BSZ) atomicAdd(&binU[r1], w.y * dinv[kc.y]);
            if ((unsigned)r2 < (unsigned)BSZ) atomicAdd(&binU[r2], w.z * dinv[kc.z]);
            if ((unsigned)r3 < (unsigned)BSZ) atomicAdd(&binU[r3], w.w * dinv[kc.w]);
        }
    }
    __syncthreads();
    {
        float4* dS = (float4*)(pA + (size_t)s * NNP + lo);
        float4* dU = (float4*)(pB + (size_t)s * NNP + lo);
        for (int i = tid; i < BSZ / 4; i += 1024) { dS[i] = bS4[i]; dU[i] = bU4[i]; }
    }
    grid.sync();

    // ---------------- ph4: reduce S,U -> c,wgt in LDS; node-dot -> accg ----------------
    {
        int v4 = blk * CH4 + tid;
        if (tid < CH4) {
            float4 cc = make_float4(0.f, 0.f, 0.f, 0.f);
            float4 ww = make_float4(0.f, 0.f, 0.f, 0.f);
            if (v4 < NNP4) {
                float4 S = make_float4(0.f, 0.f, 0.f, 0.f);
                float4 U = make_float4(0.f, 0.f, 0.f, 0.f);
                #pragma unroll
                for (int ss = 0; ss < P; ++ss) {
                    float4 a = ((const float4*)(pA + (size_t)ss * NNP))[v4];
                    float4 u = ((const float4*)(pB + (size_t)ss * NNP))[v4];
                    S.x += a.x; S.y += a.y; S.z += a.z; S.w += a.w;
                    U.x += u.x; U.y += u.y; U.z += u.z; U.w += u.w;
                }
                float4 dv = ((const float4*)dinv)[v4];
                cc.x = dv.x * (S.x + dv.x); cc.y = dv.y * (S.y + dv.y);
                cc.z = dv.z * (S.z + dv.z); cc.w = dv.w * (S.w + dv.w);
                ww.x = dv.x * (U.x + dv.x); ww.y = dv.y * (U.y + dv.y);
                ww.z = dv.z * (U.z + dv.z); ww.w = dv.w * (U.w + dv.w);
                int v0 = v4 * 4;                       // mask padded fake nodes
                if (v0 + 0 >= NN) ww.x = 0.f;
                if (v0 + 1 >= NN) ww.y = 0.f;
                if (v0 + 2 >= NN) ww.z = 0.f;
                if (v0 + 3 >= NN) ww.w = 0.f;
            }
            ((float4*)ldsC)[tid] = cc;
            ((float4*)ldsW)[tid] = ww;
        }
        __syncthreads();
        int j = tid & (D - 1), g = tid >> 7;
        float sj = s1g[j], bj = b1[j];
        float acc = 0.f;
        for (int q = g; q < CH4 * 4; q += 8) {        // uniform LDS broadcast per group
            acc += ldsW[q] * fmaxf(fmaf(ldsC[q], sj, bj), 0.f);
        }
        red[tid] = acc;
        __syncthreads();
        if (g == 0) {
            float t = acc;
            #pragma unroll
            for (int k = 1; k < 8; ++k) t += red[k * D + j];
            atomicAdd(&accg[j], t);                   // 128 floats, 256 blocks: cheap
        }
    }
    grid.sync();

    // ---------------- ph5: out = accg @ W2 / N + b2  (block 0) ----------------
    if (blk == 0) {
        if (tid < D) binS[tid] = accg[tid];
        __syncthreads();
        int j = tid & (D - 1), g = tid >> 7;
        float o = 0.f;
        #pragma unroll
        for (int k = 0; k < D / 8; ++k) {
            int jj = g * (D / 8) + k;
            o = fmaf(binS[jj], W2[jj * D + j], o);
        }
        red[tid] = o;
        __syncthreads();
        if (tid < D) {
            float t = 0.f;
            #pragma unroll
            for (int k = 0; k < 8; ++k) t += red[k * D + tid];
            out[tid] = t * (1.0f / (float)NN) + b2[tid];
        }
    }
}

extern "C" void kernel_launch(void* const* d_in, const int* in_sizes, int n_in,
                              void* d_out, int out_size, void* d_ws, size_t ws_size,
                              hipStream_t stream) {
    // inputs: 0=x (unused; ref overwrites with ones), 1=edge_index [2,E] int,
    //         2=edge_attr [E] f32, 3=W1, 4=b1, 5=W2, 6=b2 (all f32)
    const int* ei   = (const int*)d_in[1];
    const int4* row4 = (const int4*)ei;
    const int4* col4 = (const int4*)(ei + NE);
    const float4* w4 = (const float4*)d_in[2];
    const float* W1 = (const float*)d_in[3];
    const float* b1 = (const float*)d_in[4];
    const float* W2 = (const float*)d_in[5];
    const float* b2 = (const float*)d_in[6];
    float* out = (float*)d_out;

    float* ws   = (float*)d_ws;
    float* pA   = ws;                        // [P*NNP] deg partials, then S partials
    float* pB   = pA + (size_t)P * NNP;      // [P*NNP] U partials
    float* dinv = pB + (size_t)P * NNP;      // [NNP] (padded for float4 stores)
    float* s1g  = dinv + NNP;                // [D]
    float* accg = s1g + D;                   // [D]
    // total ~13.2 MB << ws_size (~256 MiB)

    void* args[] = {(void*)&col4, (void*)&row4, (void*)&w4, (void*)&W1, (void*)&b1,
                    (void*)&W2, (void*)&b2, (void*)&pA, (void*)&pB, (void*)&dinv,
                    (void*)&s1g, (void*)&accg, (void*)&out};
    hipLaunchCooperativeKernel((void*)k_fused, dim3(GRID), dim3(1024), args, 0, stream);
}

// Round 7
// 160.725 us; speedup vs baseline: 1.8497x; 1.8497x over previous
//
#include <hip/hip_runtime.h>

#define NN    100000
#define NE    1600000
#define D     128
#define P     32                 // edge slices
#define BINS  8                  // node bins
#define BSZ   12512              // nodes per bin (50 KB LDS); BINS*BSZ = 100096 >= NN
#define NNP   (BINS * BSZ)       // padded node stride (100096)
#define NNP4  (NNP / 4)          // 25024
#define SL4   (NE / 4 / P)       // int4 edges per slice = 12500 (exact)
#define RB    391                // red2node blocks: 391*64 float4 == NNP4 exactly

// XCD swizzle: blocks scanning the same edge slice s land on one XCD (blk%8 == s%8),
// so each 600 KB slice is HBM-fetched once and L2-served to the other 7 bin-blocks.
__device__ __forceinline__ void decode(int blk, int& b, int& s) {
    int x = blk & 7, y = blk >> 3;     // y in [0,32)
    s = (y & 3) * 8 + x;               // slice  [0,32)
    b = y >> 2;                        // bin    [0,8)
}

// ---- scatter 1: degree partials pA[s][v] = sum_{col=v, e in slice s} w[e] ----
__global__ __launch_bounds__(1024) void k_scat1(const int4* __restrict__ col4,
                                                const float4* __restrict__ w4,
                                                float* __restrict__ pA) {
    __shared__ float bin[BSZ];         // 50 KB -> 2 blocks/CU (32 waves)
    int b, s; decode(blockIdx.x, b, s);
    float4* bin4 = (float4*)bin;
    for (int i = threadIdx.x; i < BSZ / 4; i += 1024) bin4[i] = make_float4(0, 0, 0, 0);
    __syncthreads();
    const int lo = b * BSZ;
    const int e1 = (s + 1) * SL4;
    for (int e = s * SL4 + threadIdx.x; e < e1; e += 1024) {
        int4 k = col4[e];
        float4 v = w4[e];
        int r0 = k.x - lo, r1 = k.y - lo, r2 = k.z - lo, r3 = k.w - lo;
        if ((unsigned)r0 < (unsigned)BSZ) atomicAdd(&bin[r0], v.x);
        if ((unsigned)r1 < (unsigned)BSZ) atomicAdd(&bin[r1], v.y);
        if ((unsigned)r2 < (unsigned)BSZ) atomicAdd(&bin[r2], v.z);
        if ((unsigned)r3 < (unsigned)BSZ) atomicAdd(&bin[r3], v.w);
    }
    __syncthreads();
    float4* dst = (float4*)(pA + (size_t)s * NNP + lo);
    for (int i = threadIdx.x; i < BSZ / 4; i += 1024) dst[i] = bin4[i];
}

// ---- reduce 1: dinv = rsqrt(1 + sum_s pA[s][v]); block 0: s1 = colsum(W1), accg = 0 ----
__global__ __launch_bounds__(256) void k_red1(const float* __restrict__ pA,
                                              const float* __restrict__ W1,
                                              float* __restrict__ dinv,
                                              float* __restrict__ s1,
                                              float* __restrict__ accg) {
    int v4 = blockIdx.x * 256 + threadIdx.x;
    if (v4 < NNP4) {
        float4 a = make_float4(1.f, 1.f, 1.f, 1.f);   // self-loop weight
        #pragma unroll 8
        for (int ss = 0; ss < P; ++ss) {
            float4 p = ((const float4*)(pA + (size_t)ss * NNP))[v4];
            a.x += p.x; a.y += p.y; a.z += p.z; a.w += p.w;
        }
        float4 r;
        r.x = rsqrtf(a.x); r.y = rsqrtf(a.y); r.z = rsqrtf(a.z); r.w = rsqrtf(a.w);
        ((float4*)dinv)[v4] = r;
    }
    if (blockIdx.x == 0 && threadIdx.x < D) {
        int j = threadIdx.x;
        float sv = 0.f;
        for (int r = 0; r < D; ++r) sv += W1[r * D + j];
        s1[j] = sv;
        accg[j] = 0.f;                 // ws is re-poisoned before every call
    }
}

// ---- scatter 2 (fused): S[v]=sum_{col=v} w*dinv[row], U[v]=sum_{row=v} w*dinv[col] ----
__global__ __launch_bounds__(1024) void k_scat2(const int4* __restrict__ col4,
                                                const int4* __restrict__ row4,
                                                const float4* __restrict__ w4,
                                                const float* __restrict__ dinv,
                                                float* __restrict__ pS,
                                                float* __restrict__ pU) {
    __shared__ float binS[BSZ];
    __shared__ float binU[BSZ];        // 100 KB -> 1 block/CU (16 waves)
    int b, s; decode(blockIdx.x, b, s);
    float4* bS4 = (float4*)binS;
    float4* bU4 = (float4*)binU;
    for (int i = threadIdx.x; i < BSZ / 4; i += 1024) {
        bS4[i] = make_float4(0, 0, 0, 0);
        bU4[i] = make_float4(0, 0, 0, 0);
    }
    __syncthreads();
    const int lo = b * BSZ;
    const int e1 = (s + 1) * SL4;
    for (int e = s * SL4 + threadIdx.x; e < e1; e += 1024) {
        int4 kc = col4[e];
        int4 kr = row4[e];
        float4 w = w4[e];
        int c0 = kc.x - lo, c1 = kc.y - lo, c2 = kc.z - lo, c3 = kc.w - lo;
        int r0 = kr.x - lo, r1 = kr.y - lo, r2 = kr.z - lo, r3 = kr.w - lo;
        if ((unsigned)c0 < (unsigned)BSZ) atomicAdd(&binS[c0], w.x * dinv[kr.x]);
        if ((unsigned)c1 < (unsigned)BSZ) atomicAdd(&binS[c1], w.y * dinv[kr.y]);
        if ((unsigned)c2 < (unsigned)BSZ) atomicAdd(&binS[c2], w.z * dinv[kr.z]);
        if ((unsigned)c3 < (unsigned)BSZ) atomicAdd(&binS[c3], w.w * dinv[kr.w]);
        if ((unsigned)r0 < (unsigned)BSZ) atomicAdd(&binU[r0], w.x * dinv[kc.x]);
        if ((unsigned)r1 < (unsigned)BSZ) atomicAdd(&binU[r1], w.y * dinv[kc.y]);
        if ((unsigned)r2 < (unsigned)BSZ) atomicAdd(&binU[r2], w.z * dinv[kc.z]);
        if ((unsigned)r3 < (unsigned)BSZ) atomicAdd(&binU[r3], w.w * dinv[kc.w]);
    }
    __syncthreads();
    float4* dS = (float4*)(pS + (size_t)s * NNP + lo);
    float4* dU = (float4*)(pU + (size_t)s * NNP + lo);
    for (int i = threadIdx.x; i < BSZ / 4; i += 1024) { dS[i] = bS4[i]; dU[i] = bU4[i]; }
}

// ---- reduce 2 + node-dot (c/wgt never hit HBM):
//  c = dinv*(S+dinv), wgt = dinv*(U+dinv);  accg[j] += sum_v wgt*relu(c*s1[j]+b1[j])
__global__ __launch_bounds__(256) void k_red2node(const float* __restrict__ pS,
                                                  const float* __restrict__ pU,
                                                  const float* __restrict__ dinv,
                                                  const float* __restrict__ s1,
                                                  const float* __restrict__ b1,
                                                  float* __restrict__ accg) {
    __shared__ float4 sS[256], sU[256];       // 4-way slice-split partials
    __shared__ float4 ldsC[64], ldsW[64];     // 256 nodes per block
    __shared__ float red[D];
    const int t = threadIdx.x;
    const int q = t & 63;                     // float4 index within block chunk
    const int grp = t >> 6;                   // 0..3: slice sub-range
    const int v4 = blockIdx.x * 64 + q;       // 391*64 == NNP4 exactly

    // phase A: all 256 threads reduce 8 slices each of S and U
    float4 S = make_float4(0, 0, 0, 0), U = make_float4(0, 0, 0, 0);
    #pragma unroll
    for (int k = 0; k < P / 4; ++k) {
        int ss = grp * (P / 4) + k;
        float4 a = ((const float4*)(pS + (size_t)ss * NNP))[v4];
        float4 u = ((const float4*)(pU + (size_t)ss * NNP))[v4];
        S.x += a.x; S.y += a.y; S.z += a.z; S.w += a.w;
        U.x += u.x; U.y += u.y; U.z += u.z; U.w += u.w;
    }
    sS[t] = S; sU[t] = U;
    __syncthreads();
    if (t < 64) {
        float4 S0 = sS[t], S1 = sS[64 + t], S2 = sS[128 + t], S3 = sS[192 + t];
        float4 U0 = sU[t], U1 = sU[64 + t], U2 = sU[128 + t], U3 = sU[192 + t];
        float4 Sa, Ua;
        Sa.x = S0.x + S1.x + S2.x + S3.x; Sa.y = S0.y + S1.y + S2.y + S3.y;
        Sa.z = S0.z + S1.z + S2.z + S3.z; Sa.w = S0.w + S1.w + S2.w + S3.w;
        Ua.x = U0.x + U1.x + U2.x + U3.x; Ua.y = U0.y + U1.y + U2.y + U3.y;
        Ua.z = U0.z + U1.z + U2.z + U3.z; Ua.w = U0.w + U1.w + U2.w + U3.w;
        float4 dv = ((const float4*)dinv)[v4];
        float4 cc, ww;
        cc.x = dv.x * (Sa.x + dv.x); cc.y = dv.y * (Sa.y + dv.y);
        cc.z = dv.z * (Sa.z + dv.z); cc.w = dv.w * (Sa.w + dv.w);
        ww.x = dv.x * (Ua.x + dv.x); ww.y = dv.y * (Ua.y + dv.y);
        ww.z = dv.z * (Ua.z + dv.z); ww.w = dv.w * (Ua.w + dv.w);
        int v0 = v4 * 4;                      // mask padded fake nodes (v >= NN)
        if (v0 + 0 >= NN) ww.x = 0.f;
        if (v0 + 1 >= NN) ww.y = 0.f;
        if (v0 + 2 >= NN) ww.z = 0.f;
        if (v0 + 3 >= NN) ww.w = 0.f;
        ldsC[t] = cc; ldsW[t] = ww;
    }
    __syncthreads();

    // phase B: node-dot. 2 j-groups of 128 lanes; group g scans 32 float4 node-packs.
    const int j = t & (D - 1), g = t >> 7;
    const float sj = s1[j], bj = b1[j];
    float acc = 0.f;
    #pragma unroll
    for (int k = 0; k < 32; ++k) {
        float4 c4 = ldsC[g * 32 + k];         // wave-uniform LDS broadcast
        float4 w4 = ldsW[g * 32 + k];
        acc += w4.x * fmaxf(fmaf(c4.x, sj, bj), 0.f);
        acc += w4.y * fmaxf(fmaf(c4.y, sj, bj), 0.f);
        acc += w4.z * fmaxf(fmaf(c4.z, sj, bj), 0.f);
        acc += w4.w * fmaxf(fmaf(c4.w, sj, bj), 0.f);
    }
    if (g) red[j] = acc;
    __syncthreads();
    if (!g) atomicAdd(&accg[j], acc + red[j]);   // 128 atomics/block, 391 blocks
}

// ---- gemv: out[k] = (1/N) * sum_j accg[j]*W2[j][k] + b2[k] ----
__global__ __launch_bounds__(256) void k_gemv(const float* __restrict__ accg,
                                              const float* __restrict__ W2,
                                              const float* __restrict__ b2,
                                              float* __restrict__ out) {
    __shared__ float a[D], r2[D];
    int t = threadIdx.x, k = t & (D - 1), g = t >> 7;
    if (t < D) a[t] = accg[t];
    __syncthreads();
    float o = 0.f;
    int j0 = g * 64;
    #pragma unroll 16
    for (int j = j0; j < j0 + 64; ++j) o = fmaf(a[j], W2[j * D + k], o);
    if (g) r2[k] = o;
    __syncthreads();
    if (!g) out[k] = (o + r2[k]) * (1.0f / (float)NN) + b2[k];
}

extern "C" void kernel_launch(void* const* d_in, const int* in_sizes, int n_in,
                              void* d_out, int out_size, void* d_ws, size_t ws_size,
                              hipStream_t stream) {
    // inputs: 0=x (unused; ref overwrites with ones), 1=edge_index [2,E] int,
    //         2=edge_attr [E] f32, 3=W1, 4=b1, 5=W2, 6=b2 (all f32)
    const int* ei    = (const int*)d_in[1];
    const int4* row4 = (const int4*)ei;
    const int4* col4 = (const int4*)(ei + NE);
    const float4* w4 = (const float4*)d_in[2];
    const float* W1 = (const float*)d_in[3];
    const float* b1 = (const float*)d_in[4];
    const float* W2 = (const float*)d_in[5];
    const float* b2 = (const float*)d_in[6];
    float* out = (float*)d_out;

    float* ws   = (float*)d_ws;
    float* pA   = ws;                        // [P*NNP] deg partials, then S partials
    float* pB   = pA + (size_t)P * NNP;      // [P*NNP] U partials
    float* dinv = pB + (size_t)P * NNP;      // [NNP]
    float* s1   = dinv + NNP;                // [D]
    float* accg = s1 + D;                    // [D]
    // total ~26 MB << ws_size

    k_scat1   <<<BINS * P, 1024, 0, stream>>>(col4, w4, pA);
    k_red1    <<<(NNP4 + 255) / 256, 256, 0, stream>>>(pA, W1, dinv, s1, accg);
    k_scat2   <<<BINS * P, 1024, 0, stream>>>(col4, row4, w4, dinv, pA, pB);
    k_red2node<<<RB, 256, 0, stream>>>(pA, pB, dinv, s1, b1, accg);
    k_gemv    <<<1, 256, 0, stream>>>(accg, W2, b2, out);
}